// Round 1
// baseline (143.974 us; speedup 1.0000x reference)
//
#include <hip/hip_runtime.h>
#include <stdint.h>

#define NBINS 100
#define FF 16
#define CC 16

// ---------- workspace layout (bytes) ----------
// [0      ) unsigned minmax[32]      : 16 min-encoded, 16 max-encoded   (128 B)
// [128    ) float    edges[16*101]   : 6464 B
// [6592   ) unsigned counts[16*100]  : 6400 B
// [12992  ) float    cum[16*100]     : 6400 B
// [19392  ) int      cbins[16*16]    : 1024 B
// total 20416 B

// order-preserving float<->uint encoding (no NaNs in inputs)
__device__ __forceinline__ unsigned enc_f(float v) {
    unsigned u = __float_as_uint(v);
    return (u & 0x80000000u) ? ~u : (u | 0x80000000u);
}
__device__ __forceinline__ float dec_f(unsigned e) {
    unsigned u = (e & 0x80000000u) ? (e ^ 0x80000000u) : ~e;
    return __uint_as_float(u);
}

__global__ __launch_bounds__(256) void k_init(unsigned* minmax, unsigned* counts) {
    int t = threadIdx.x;
    if (t < 16) { minmax[t] = 0xFFFFFFFFu; minmax[16 + t] = 0u; }
    for (int i = t; i < FF * NBINS; i += 256) counts[i] = 0u;
}

// per-feature min/max over combined = [z; cluster_layer]
__global__ __launch_bounds__(256) void k_minmax(const float* __restrict__ z,
                                                const float* __restrict__ cl,
                                                int N, unsigned* minmax) {
    int total = (N + CC) * FF;
    int zn = N * FF;
    int gtid = blockIdx.x * 256 + threadIdx.x;
    int stride = gridDim.x * 256;   // multiple of 16 -> f fixed per thread
    unsigned umin = 0xFFFFFFFFu, umax = 0u;
    for (int i = gtid; i < total; i += stride) {
        float v = (i < zn) ? z[i] : cl[i - zn];
        unsigned e = enc_f(v);
        umin = min(umin, e);
        umax = max(umax, e);
    }
    // lanes l, l+16, l+32, l+48 share feature f = l%16 -> butterfly over 16,32
    umin = min(umin, (unsigned)__shfl_xor((int)umin, 16, 64));
    umax = max(umax, (unsigned)__shfl_xor((int)umax, 16, 64));
    umin = min(umin, (unsigned)__shfl_xor((int)umin, 32, 64));
    umax = max(umax, (unsigned)__shfl_xor((int)umax, 32, 64));
    __shared__ unsigned smin[4][16], smax[4][16];
    int wave = threadIdx.x >> 6, lane = threadIdx.x & 63;
    if (lane < 16) { smin[wave][lane] = umin; smax[wave][lane] = umax; }
    __syncthreads();
    if (threadIdx.x < 16) {
        int f = threadIdx.x;
        unsigned m0 = min(min(smin[0][f], smin[1][f]), min(smin[2][f], smin[3][f]));
        unsigned m1 = max(max(smax[0][f], smax[1][f]), max(smax[2][f], smax[3][f]));
        atomicMin(&minmax[f], m0);
        atomicMax(&minmax[16 + f], m1);
    }
}

// edges[f][k] = lo + (hi-lo) * t_k ; t_k = k*0.01f (f32), t_100 = 1.0f  (JAX linspace)
// explicit _rn intrinsics forbid fma contraction so we match mul-then-add f32.
__global__ __launch_bounds__(256) void k_edges(const unsigned* __restrict__ minmax,
                                               float* __restrict__ edges) {
    for (int i = threadIdx.x; i < FF * (NBINS + 1); i += 256) {
        int f = i / (NBINS + 1), k = i % (NBINS + 1);
        float lo = dec_f(minmax[f]);
        float hi = dec_f(minmax[16 + f]);
        float t = (k == NBINS) ? 1.0f : __fmul_rn((float)k, 0.01f);
        edges[i] = __fadd_rn(lo, __fmul_rn(__fsub_rn(hi, lo), t));
    }
}

// histogram: searchsorted(edges, v, side='right') - 1, clipped to [0,99]
__global__ __launch_bounds__(256) void k_hist(const float* __restrict__ z,
                                              const float* __restrict__ cl,
                                              int N, const float* __restrict__ edges,
                                              unsigned* __restrict__ counts) {
    __shared__ float se[FF * (NBINS + 1)];
    __shared__ unsigned sc[FF * NBINS];
    for (int i = threadIdx.x; i < FF * (NBINS + 1); i += 256) se[i] = edges[i];
    for (int i = threadIdx.x; i < FF * NBINS; i += 256) sc[i] = 0u;
    __syncthreads();
    int total = (N + CC) * FF;
    int zn = N * FF;
    int gtid = blockIdx.x * 256 + threadIdx.x;
    int stride = gridDim.x * 256;
    int f = threadIdx.x & 15;                 // fixed per thread (stride % 16 == 0)
    const float* ef = &se[f * (NBINS + 1)];
    unsigned* cf = &sc[f * NBINS];
    for (int i = gtid; i < total; i += stride) {
        float v = (i < zn) ? z[i] : cl[i - zn];
        int lo = 0, hi = NBINS + 1;           // first index with e[idx] > v
        while (lo < hi) { int mid = (lo + hi) >> 1; if (ef[mid] <= v) lo = mid + 1; else hi = mid; }
        int idx = lo - 1;
        idx = idx < 0 ? 0 : (idx > NBINS - 1 ? NBINS - 1 : idx);
        atomicAdd(&cf[idx], 1u);
    }
    __syncthreads();
    for (int i = threadIdx.x; i < FF * NBINS; i += 256) {
        unsigned c = sc[i];
        if (c) atomicAdd(&counts[i], c);
    }
}

// cumsum of counts (f32, exact: total < 2^24) + cluster bins (side='left')
__global__ __launch_bounds__(256) void k_cum_cbins(const unsigned* __restrict__ counts,
                                                   const float* __restrict__ edges,
                                                   const float* __restrict__ cl,
                                                   float* __restrict__ cum,
                                                   int* __restrict__ cbins) {
    int t = threadIdx.x;
    if (t < FF) {
        float s = 0.0f;
        for (int k = 0; k < NBINS; ++k) {
            s += (float)counts[t * NBINS + k];
            cum[t * NBINS + k] = s;
        }
    }
    if (t < CC * FF) {
        int c = t >> 4, f = t & 15;
        float v = cl[c * FF + f];
        const float* ef = &edges[f * (NBINS + 1)];
        int lo = 0, hi = NBINS + 1;           // first index with e[idx] >= v
        while (lo < hi) { int mid = (lo + hi) >> 1; if (ef[mid] < v) lo = mid + 1; else hi = mid; }
        cbins[t] = lo - 1;                    // can be -1 (v == feature min)
    }
}

// main: one thread per sample; edges/cum/cbins in LDS
__global__ __launch_bounds__(256) void k_main(const float* __restrict__ z, int N, float inv_div,
                                              const float* __restrict__ edges,
                                              const float* __restrict__ cum,
                                              const int* __restrict__ cbins,
                                              float* __restrict__ out) {
    __shared__ float se[FF * (NBINS + 1)];
    __shared__ float scum[FF * NBINS];
    __shared__ int scb[CC * FF];
    for (int i = threadIdx.x; i < FF * (NBINS + 1); i += 256) se[i] = edges[i];
    for (int i = threadIdx.x; i < FF * NBINS; i += 256) scum[i] = cum[i];
    if (threadIdx.x < CC * FF) scb[threadIdx.x] = cbins[threadIdx.x];
    __syncthreads();

    int n = blockIdx.x * 256 + threadIdx.x;
    if (n >= N) return;

    float v[FF];
    const float4* zr = (const float4*)(z + (size_t)n * FF);
    float4 a0 = zr[0], a1 = zr[1], a2 = zr[2], a3 = zr[3];
    v[0] = a0.x; v[1] = a0.y; v[2]  = a0.z; v[3]  = a0.w;
    v[4] = a1.x; v[5] = a1.y; v[6]  = a1.z; v[7]  = a1.w;
    v[8] = a2.x; v[9] = a2.y; v[10] = a2.z; v[11] = a2.w;
    v[12] = a3.x; v[13] = a3.y; v[14] = a3.z; v[15] = a3.w;

    int sb[FF];
#pragma unroll
    for (int f = 0; f < FF; ++f) {
        const float* ef = &se[f * (NBINS + 1)];
        int lo = 0, hi = NBINS + 1;           // side='left'
        while (lo < hi) { int mid = (lo + hi) >> 1; if (ef[mid] < v[f]) lo = mid + 1; else hi = mid; }
        sb[f] = lo - 1;                       // in [-1, 99]
    }

    float q[CC];
    float rowsum = 0.0f;
    for (int c = 0; c < CC; ++c) {
        float acc = 0.0f;
#pragma unroll
        for (int f = 0; f < FF; ++f) {
            int cb = scb[c * FF + f];         // wave-uniform -> LDS broadcast
            int s = sb[f];
            int mn = s < cb ? s : cb;
            int mx = s < cb ? cb : s;
            int hiIdx = mx < 0 ? 0 : (mx > NBINS - 1 ? NBINS - 1 : mx);
            float hiS = scum[f * NBINS + hiIdx];
            int loIdx = (mn <= 0) ? 0 : (mn - 1);
            float loS = scum[f * NBINS + loIdx];
            float scnt = (mn <= 0) ? hiS : (hiS - loS);
            float m = scnt * inv_div;
            acc += m * m;
        }
        float mass = sqrtf(acc);
        float qq = 1.0f / (1.0f + mass);
        q[c] = qq;
        rowsum += qq;
    }

    float inv = 1.0f / rowsum;  // reference divides; rcp-mul error ~1ulp << threshold
    (void)inv;
    float* op = out + (size_t)n * CC;
    float4 o;
    o.x = q[0] / rowsum;  o.y = q[1] / rowsum;  o.z = q[2] / rowsum;  o.w = q[3] / rowsum;
    ((float4*)op)[0] = o;
    o.x = q[4] / rowsum;  o.y = q[5] / rowsum;  o.z = q[6] / rowsum;  o.w = q[7] / rowsum;
    ((float4*)op)[1] = o;
    o.x = q[8] / rowsum;  o.y = q[9] / rowsum;  o.z = q[10] / rowsum; o.w = q[11] / rowsum;
    ((float4*)op)[2] = o;
    o.x = q[12] / rowsum; o.y = q[13] / rowsum; o.z = q[14] / rowsum; o.w = q[15] / rowsum;
    ((float4*)op)[3] = o;
}

extern "C" void kernel_launch(void* const* d_in, const int* in_sizes, int n_in,
                              void* d_out, int out_size, void* d_ws, size_t ws_size,
                              hipStream_t stream) {
    const float* z  = (const float*)d_in[0];
    const float* cl = (const float*)d_in[1];
    float* out = (float*)d_out;
    int N = in_sizes[0] / FF;

    char* ws = (char*)d_ws;
    unsigned* minmax = (unsigned*)(ws);
    float*    edges  = (float*)(ws + 128);
    unsigned* counts = (unsigned*)(ws + 6592);
    float*    cum    = (float*)(ws + 12992);
    int*      cbins  = (int*)(ws + 19392);

    float inv_div = 1.0f / (float)(N + CC);

    k_init<<<1, 256, 0, stream>>>(minmax, counts);
    k_minmax<<<64, 256, 0, stream>>>(z, cl, N, minmax);
    k_edges<<<1, 256, 0, stream>>>(minmax, edges);
    k_hist<<<128, 256, 0, stream>>>(z, cl, N, edges, counts);
    k_cum_cbins<<<1, 256, 0, stream>>>(counts, edges, cl, cum, cbins);
    int blocks = (N + 255) / 256;
    k_main<<<blocks, 256, 0, stream>>>(z, N, inv_div, edges, cum, cbins, out);
}

// Round 2
// 111.494 us; speedup vs baseline: 1.2913x; 1.2913x over previous
//
#include <hip/hip_runtime.h>
#include <stdint.h>

#define NBINS 100
#define FF 16
#define CC 16
#define MM_BLOCKS 128
#define HIST_BLOCKS 256

// ---------- workspace layout (bytes) ----------
// [0     ) unsigned partials[128*32]  : 16384 B  (per-block min/max, encoded)
// [16384 ) float    edges[16*101]     : 6464 B
// [22848 ) float    scale[16]         : 64 B
// [22912 ) unsigned counts[16*100]    : 6400 B
// [29312 ) float    cum[16*100]       : 6400 B
// [35712 ) float2   qpc[16*16]        : 2048 B   (Qc,Pc per (c,f))
// total 37760 B

// order-preserving float<->uint encoding (no NaNs in inputs)
__device__ __forceinline__ unsigned enc_f(float v) {
    unsigned u = __float_as_uint(v);
    return (u & 0x80000000u) ? ~u : (u | 0x80000000u);
}
__device__ __forceinline__ float dec_f(unsigned e) {
    unsigned u = (e & 0x80000000u) ? (e ^ 0x80000000u) : ~e;
    return __uint_as_float(u);
}

// per-feature min/max partials over combined = [z; cluster_layer]; no init needed
__global__ __launch_bounds__(256) void k_minmax(const float* __restrict__ z,
                                                const float* __restrict__ cl,
                                                int N, unsigned* __restrict__ partials) {
    int total = (N + CC) * FF;
    int zn = N * FF;
    int gtid = blockIdx.x * 256 + threadIdx.x;
    int stride = gridDim.x * 256;   // multiple of 16 -> feature fixed per thread
    unsigned umin = 0xFFFFFFFFu, umax = 0u;
    for (int i = gtid; i < total; i += stride) {
        float v = (i < zn) ? z[i] : cl[i - zn];
        unsigned e = enc_f(v);
        umin = min(umin, e);
        umax = max(umax, e);
    }
    umin = min(umin, (unsigned)__shfl_xor((int)umin, 16, 64));
    umax = max(umax, (unsigned)__shfl_xor((int)umax, 16, 64));
    umin = min(umin, (unsigned)__shfl_xor((int)umin, 32, 64));
    umax = max(umax, (unsigned)__shfl_xor((int)umax, 32, 64));
    __shared__ unsigned smin[4][16], smax[4][16];
    int wave = threadIdx.x >> 6, lane = threadIdx.x & 63;
    if (lane < 16) { smin[wave][lane] = umin; smax[wave][lane] = umax; }
    __syncthreads();
    if (threadIdx.x < 16) {
        int f = threadIdx.x;
        partials[blockIdx.x * 32 + f] =
            min(min(smin[0][f], smin[1][f]), min(smin[2][f], smin[3][f]));
        partials[blockIdx.x * 32 + 16 + f] =
            max(max(smax[0][f], smax[1][f]), max(smax[2][f], smax[3][f]));
    }
}

// reduce partials -> edges (exact JAX linspace arithmetic), scale, zero counts
__global__ __launch_bounds__(256) void k_prep(const unsigned* __restrict__ partials,
                                              float* __restrict__ edges,
                                              float* __restrict__ scale,
                                              unsigned* __restrict__ counts) {
    __shared__ float slo[16], shi[16];
    int t = threadIdx.x;
    if (t < 16) {
        unsigned um = 0xFFFFFFFFu, ux = 0u;
#pragma unroll 8
        for (int b = 0; b < MM_BLOCKS; ++b) {
            um = min(um, partials[b * 32 + t]);
            ux = max(ux, partials[b * 32 + 16 + t]);
        }
        slo[t] = dec_f(um);
        shi[t] = dec_f(ux);
    }
    __syncthreads();
    for (int i = t; i < FF * (NBINS + 1); i += 256) {
        int f = i / (NBINS + 1), k = i - f * (NBINS + 1);
        float lo = slo[f], hi = shi[f];
        float tt = (k == NBINS) ? 1.0f : __fmul_rn((float)k, 0.01f);
        edges[i] = __fadd_rn(lo, __fmul_rn(__fsub_rn(hi, lo), tt));
    }
    if (t < 16) {
        float d = shi[t] - slo[t];
        scale[t] = d > 0.0f ? 100.0f / d : 0.0f;
    }
    for (int i = t; i < FF * NBINS; i += 256) counts[i] = 0u;
}

// histogram: searchsorted(edges, v, 'right')-1 clipped, via division guess + fixup
__global__ __launch_bounds__(256) void k_hist(const float* __restrict__ z,
                                              const float* __restrict__ cl,
                                              int N, const float* __restrict__ edges,
                                              const float* __restrict__ scale,
                                              unsigned* __restrict__ counts) {
    __shared__ float se[FF * (NBINS + 1)];
    __shared__ float ss[16];
    __shared__ unsigned sc[FF * NBINS];
    for (int i = threadIdx.x; i < FF * (NBINS + 1); i += 256) se[i] = edges[i];
    if (threadIdx.x < 16) ss[threadIdx.x] = scale[threadIdx.x];
    for (int i = threadIdx.x; i < FF * NBINS; i += 256) sc[i] = 0u;
    __syncthreads();
    int total = (N + CC) * FF;
    int zn = N * FF;
    int gtid = blockIdx.x * 256 + threadIdx.x;
    int stride = gridDim.x * 256;   // multiple of 16
    int f = threadIdx.x & 15;
    const float* ef = &se[f * (NBINS + 1)];
    unsigned* cf = &sc[f * NBINS];
    float lo0 = ef[0], scl = ss[f];
    for (int i = gtid; i < total; i += stride) {
        float v = (i < zn) ? z[i] : cl[i - zn];
        int g = (int)((v - lo0) * scl);
        g = g < 0 ? 0 : (g > NBINS - 1 ? NBINS - 1 : g);
        while (g < NBINS - 1 && ef[g + 1] <= v) ++g;   // side='right' fixup
        while (g > 0 && ef[g] > v) --g;
        atomicAdd(&cf[g], 1u);
    }
    __syncthreads();
    for (int i = threadIdx.x; i < FF * NBINS; i += 256) {
        unsigned c = sc[i];
        if (c) atomicAdd(&counts[i], c);
    }
}

// cumsum (f32, exact: total < 2^24) + cluster-side (Qc,Pc) table
__global__ __launch_bounds__(256) void k_post(const unsigned* __restrict__ counts,
                                              const float* __restrict__ edges,
                                              const float* __restrict__ scale,
                                              const float* __restrict__ cl,
                                              float* __restrict__ cum,
                                              float2* __restrict__ qpc) {
    int t = threadIdx.x;
    if (t < FF) {
        float s = 0.0f;
#pragma unroll
        for (int k = 0; k < NBINS; ++k) {
            s += (float)counts[t * NBINS + k];
            cum[t * NBINS + k] = s;
        }
    }
    __syncthreads();
    // 256 threads = 16 clusters x 16 features; searchsorted side='left' - 1
    int c = t >> 4, f = t & 15;
    float v = cl[c * FF + f];
    const float* ef = &edges[f * (NBINS + 1)];
    int g = (int)((v - ef[0]) * scale[f]);
    g = g < 0 ? 0 : (g > NBINS - 1 ? NBINS - 1 : g);
    while (g < NBINS - 1 && ef[g + 1] < v) ++g;
    while (g >= 0 && ef[g] >= v) --g;          // g in [-1, 99]
    float Qc = cum[f * NBINS + (g < 0 ? 0 : g)];
    float Pc = (g >= 1) ? cum[f * NBINS + g - 1] : 0.0f;
    qpc[t] = make_float2(Qc, Pc);
}

// main: one thread per sample.
// scnt(s,cb) = cum[clamp(max,0,99)] - (min<=0 ? 0 : cum[min-1])
//            = max(Qs,Qc) - min(Ps,Pc)   (Q,P monotone in bin index; exact identity)
__global__ __launch_bounds__(256) void k_main(const float* __restrict__ z, int N, float inv_div,
                                              const float* __restrict__ edges,
                                              const float* __restrict__ scale,
                                              const float* __restrict__ cum,
                                              const float2* __restrict__ qpc,
                                              float* __restrict__ out) {
    __shared__ float se[FF * (NBINS + 1)];
    __shared__ float ss[16];
    __shared__ float scum[FF * NBINS];
    __shared__ float2 sqp[CC * FF];
    for (int i = threadIdx.x; i < FF * (NBINS + 1); i += 256) se[i] = edges[i];
    if (threadIdx.x < 16) ss[threadIdx.x] = scale[threadIdx.x];
    for (int i = threadIdx.x; i < FF * NBINS; i += 256) scum[i] = cum[i];
    if (threadIdx.x < CC * FF) sqp[threadIdx.x] = qpc[threadIdx.x];
    __syncthreads();

    int n = blockIdx.x * 256 + threadIdx.x;
    if (n >= N) return;

    float v[FF];
    const float4* zr = (const float4*)(z + (size_t)n * FF);
    float4 a0 = zr[0], a1 = zr[1], a2 = zr[2], a3 = zr[3];
    v[0] = a0.x; v[1] = a0.y; v[2]  = a0.z; v[3]  = a0.w;
    v[4] = a1.x; v[5] = a1.y; v[6]  = a1.z; v[7]  = a1.w;
    v[8] = a2.x; v[9] = a2.y; v[10] = a2.z; v[11] = a2.w;
    v[12] = a3.x; v[13] = a3.y; v[14] = a3.z; v[15] = a3.w;

    float Qs[FF], Ps[FF];
#pragma unroll
    for (int f = 0; f < FF; ++f) {
        const float* ef = &se[f * (NBINS + 1)];
        int g = (int)((v[f] - ef[0]) * ss[f]);
        g = g < 0 ? 0 : (g > NBINS - 1 ? NBINS - 1 : g);
        while (g < NBINS - 1 && ef[g + 1] < v[f]) ++g;   // side='left' fixup
        while (g >= 0 && ef[g] >= v[f]) --g;             // g in [-1, 99]
        Qs[f] = scum[f * NBINS + (g < 0 ? 0 : g)];
        Ps[f] = (g >= 1) ? scum[f * NBINS + g - 1] : 0.0f;
    }

    float q[CC];
    float rowsum = 0.0f;
#pragma unroll
    for (int c = 0; c < CC; ++c) {
        float acc = 0.0f;
#pragma unroll
        for (int f = 0; f < FF; ++f) {
            float2 qp = sqp[c * FF + f];       // wave-uniform -> LDS broadcast
            float h = fmaxf(Qs[f], qp.x);
            float l = fminf(Ps[f], qp.y);
            float d = h - l;
            acc = fmaf(d, d, acc);
        }
        float mass = sqrtf(acc) * inv_div;     // sqrt(sum scnt^2) / divisor
        float qq = 1.0f / (1.0f + mass);
        q[c] = qq;
        rowsum += qq;
    }

    float* op = out + (size_t)n * CC;
    float4 o;
    o.x = q[0] / rowsum;  o.y = q[1] / rowsum;  o.z = q[2] / rowsum;  o.w = q[3] / rowsum;
    ((float4*)op)[0] = o;
    o.x = q[4] / rowsum;  o.y = q[5] / rowsum;  o.z = q[6] / rowsum;  o.w = q[7] / rowsum;
    ((float4*)op)[1] = o;
    o.x = q[8] / rowsum;  o.y = q[9] / rowsum;  o.z = q[10] / rowsum; o.w = q[11] / rowsum;
    ((float4*)op)[2] = o;
    o.x = q[12] / rowsum; o.y = q[13] / rowsum; o.z = q[14] / rowsum; o.w = q[15] / rowsum;
    ((float4*)op)[3] = o;
}

extern "C" void kernel_launch(void* const* d_in, const int* in_sizes, int n_in,
                              void* d_out, int out_size, void* d_ws, size_t ws_size,
                              hipStream_t stream) {
    const float* z  = (const float*)d_in[0];
    const float* cl = (const float*)d_in[1];
    float* out = (float*)d_out;
    int N = in_sizes[0] / FF;

    char* ws = (char*)d_ws;
    unsigned* partials = (unsigned*)(ws);
    float*    edges    = (float*)(ws + 16384);
    float*    scale    = (float*)(ws + 22848);
    unsigned* counts   = (unsigned*)(ws + 22912);
    float*    cum      = (float*)(ws + 29312);
    float2*   qpc      = (float2*)(ws + 35712);

    float inv_div = 1.0f / (float)(N + CC);

    k_minmax<<<MM_BLOCKS, 256, 0, stream>>>(z, cl, N, partials);
    k_prep<<<1, 256, 0, stream>>>(partials, edges, scale, counts);
    k_hist<<<HIST_BLOCKS, 256, 0, stream>>>(z, cl, N, edges, scale, counts);
    k_post<<<1, 256, 0, stream>>>(counts, edges, scale, cl, cum, qpc);
    int blocks = (N + 255) / 256;
    k_main<<<blocks, 256, 0, stream>>>(z, N, inv_div, edges, scale, cum, qpc, out);
}

// Round 3
// 96.817 us; speedup vs baseline: 1.4871x; 1.1516x over previous
//
#include <hip/hip_runtime.h>
#include <stdint.h>

#define NBINS 100
#define FF 16
#define CC 16
#define MM_BLOCKS 128
#define HIST_BLOCKS 256

// ---------- workspace layout (bytes) ----------
// [0     ) unsigned partials[128*32]  : 16384 B  (per-block min/max, order-encoded)
// [16384 ) unsigned counts[16*100]    : 6400 B
// total 22784 B

// order-preserving float<->uint encoding (no NaNs in inputs)
__device__ __forceinline__ unsigned enc_f(float v) {
    unsigned u = __float_as_uint(v);
    return (u & 0x80000000u) ? ~u : (u | 0x80000000u);
}
__device__ __forceinline__ float dec_f(unsigned e) {
    unsigned u = (e & 0x80000000u) ? (e ^ 0x80000000u) : ~u ^ 0u;
    u = (e & 0x80000000u) ? (e ^ 0x80000000u) : ~e;
    return __uint_as_float(u);
}
__device__ __forceinline__ unsigned shfl_xor_u(unsigned x, int m) {
    return (unsigned)__shfl_xor((int)x, m, 64);
}

// K1: per-feature min/max partials over combined=[z;cl] (float4), zero counts.
__global__ __launch_bounds__(256) void k_minmax(const float4* __restrict__ z4,
                                                const float4* __restrict__ cl4,
                                                int zn4, int total4,
                                                unsigned* __restrict__ partials,
                                                unsigned* __restrict__ counts) {
    int gtid = blockIdx.x * 256 + threadIdx.x;
    if (gtid < FF * NBINS) counts[gtid] = 0u;   // zero for K2's atomics

    unsigned mn[4] = {~0u, ~0u, ~0u, ~0u}, mx[4] = {0u, 0u, 0u, 0u};
    int stride = MM_BLOCKS * 256;               // f4 units; 4*stride % 16 == 0
    for (int i = gtid; i < total4; i += stride) {
        float4 v = (i < zn4) ? z4[i] : cl4[i - zn4];
        unsigned e;
        e = enc_f(v.x); mn[0] = min(mn[0], e); mx[0] = max(mx[0], e);
        e = enc_f(v.y); mn[1] = min(mn[1], e); mx[1] = max(mx[1], e);
        e = enc_f(v.z); mn[2] = min(mn[2], e); mx[2] = max(mx[2], e);
        e = enc_f(v.w); mn[3] = min(mn[3], e); mx[3] = max(mx[3], e);
    }
    // lane l component c covers feature (4l+c)&15; lanes l and l^4 share features
#pragma unroll
    for (int off = 4; off < 64; off <<= 1) {
#pragma unroll
        for (int c = 0; c < 4; ++c) {
            mn[c] = min(mn[c], shfl_xor_u(mn[c], off));
            mx[c] = max(mx[c], shfl_xor_u(mx[c], off));
        }
    }
    __shared__ unsigned smin[4][16], smax[4][16];
    int wave = threadIdx.x >> 6, lane = threadIdx.x & 63;
    if (lane < 4) {
#pragma unroll
        for (int c = 0; c < 4; ++c) {
            smin[wave][4 * lane + c] = mn[c];
            smax[wave][4 * lane + c] = mx[c];
        }
    }
    __syncthreads();
    if (threadIdx.x < 16) {
        int f = threadIdx.x;
        partials[blockIdx.x * 32 + f] =
            min(min(smin[0][f], smin[1][f]), min(smin[2][f], smin[3][f]));
        partials[blockIdx.x * 32 + 16 + f] =
            max(max(smax[0][f], smax[1][f]), max(smax[2][f], smax[3][f]));
    }
}

// shared preamble: reduce partials -> ulo/uhi (LDS), then edges/scale.
// Edges use exact JAX linspace arithmetic; deterministic IEEE ops -> bit-identical
// in every block of every kernel that runs this.
__device__ __forceinline__ void build_edges(const unsigned* __restrict__ partials,
                                            unsigned* ulo, unsigned* uhi,
                                            float* se, float* ss, float* slo) {
    int t = threadIdx.x;
    if (t < 16) { ulo[t] = ~0u; uhi[t] = 0u; }
    __syncthreads();
    {
        int f = t & 15, b0 = (t >> 4) * (MM_BLOCKS / 16);
        unsigned um = ~0u, ux = 0u;
#pragma unroll
        for (int b = b0; b < b0 + MM_BLOCKS / 16; ++b) {
            um = min(um, partials[b * 32 + f]);
            ux = max(ux, partials[b * 32 + 16 + f]);
        }
        atomicMin(&ulo[f], um);
        atomicMax(&uhi[f], ux);
    }
    __syncthreads();
    for (int i = t; i < FF * (NBINS + 1); i += 256) {
        int f = i / (NBINS + 1), k = i - f * (NBINS + 1);
        float lo = dec_f(ulo[f]), hi = dec_f(uhi[f]);
        float tt = (k == NBINS) ? 1.0f : __fmul_rn((float)k, 0.01f);
        se[i] = __fadd_rn(lo, __fmul_rn(__fsub_rn(hi, lo), tt));
    }
    if (t < 16) {
        float lo = dec_f(ulo[t]), hi = dec_f(uhi[t]);
        float d = hi - lo;
        ss[t] = d > 0.0f ? 100.0f / d : 0.0f;   // guess only; fixup is exact
        slo[t] = lo;
    }
    __syncthreads();
}

// K2: histogram (searchsorted 'right'-1 clipped) via guess+fixup, float4 loads.
__global__ __launch_bounds__(256) void k_hist(const float4* __restrict__ z4,
                                              const float4* __restrict__ cl4,
                                              int zn4, int total4,
                                              const unsigned* __restrict__ partials,
                                              unsigned* __restrict__ counts) {
    __shared__ unsigned ulo[16], uhi[16];
    __shared__ float se[FF * (NBINS + 1)];
    __shared__ float ss[16], slo[16];
    __shared__ unsigned sc[FF * NBINS];
    for (int i = threadIdx.x; i < FF * NBINS; i += 256) sc[i] = 0u;
    build_edges(partials, ulo, uhi, se, ss, slo);

    int gtid = blockIdx.x * 256 + threadIdx.x;
    int stride = HIST_BLOCKS * 256;             // 4*stride % 16 == 0
    int fb = (4 * gtid) & 15;                   // feature of component 0 (fixed)
    for (int i = gtid; i < total4; i += stride) {
        float4 v4 = (i < zn4) ? z4[i] : cl4[i - zn4];
        float vv[4] = {v4.x, v4.y, v4.z, v4.w};
#pragma unroll
        for (int c = 0; c < 4; ++c) {
            int f = (fb + c) & 15;
            float v = vv[c];
            const float* ef = &se[f * (NBINS + 1)];
            int g = (int)((v - slo[f]) * ss[f]);
            g = g < 0 ? 0 : (g > NBINS - 1 ? NBINS - 1 : g);
            while (g < NBINS - 1 && ef[g + 1] <= v) ++g;   // side='right'
            while (g > 0 && ef[g] > v) --g;
            atomicAdd(&sc[f * NBINS + g], 1u);
        }
    }
    __syncthreads();
    for (int i = threadIdx.x; i < FF * NBINS; i += 256) {
        unsigned c = sc[i];
        if (c) atomicAdd(&counts[i], c);
    }
}

// K3: preamble rebuilds edges + cumsum + cluster (Qc,Pc); then per-sample output.
// scnt(s,cb) = max(Qs,Qc) - min(Ps,Pc)  (exact identity, Q/P monotone in bin)
__global__ __launch_bounds__(256) void k_main(const float4* __restrict__ z4, int N,
                                              float inv_div,
                                              const unsigned* __restrict__ partials,
                                              const unsigned* __restrict__ counts,
                                              const float* __restrict__ cl,
                                              float* __restrict__ out) {
    __shared__ unsigned ulo[16], uhi[16];
    __shared__ float se[FF * (NBINS + 1)];
    __shared__ float ss[16], slo[16];
    __shared__ unsigned scnt[FF * NBINS];
    __shared__ float scum[FF * NBINS];
    __shared__ float2 sqp[CC * FF];
    int t = threadIdx.x;
    for (int i = t; i < FF * NBINS; i += 256) scnt[i] = counts[i];
    build_edges(partials, ulo, uhi, se, ss, slo);
    if (t < 16) {                                // serial cumsum, exact (ints < 2^24)
        float s = 0.0f;
        const unsigned* cp = &scnt[t * NBINS];
        float* fp = &scum[t * NBINS];
#pragma unroll
        for (int k = 0; k < NBINS; ++k) { s += (float)cp[k]; fp[k] = s; }
    }
    __syncthreads();
    {                                            // 256 threads = 16c x 16f
        int c = t >> 4, f = t & 15;
        float v = cl[c * FF + f];
        const float* ef = &se[f * (NBINS + 1)];
        int g = (int)((v - slo[f]) * ss[f]);
        g = g < 0 ? 0 : (g > NBINS - 1 ? NBINS - 1 : g);
        while (g < NBINS - 1 && ef[g + 1] < v) ++g;   // side='left'
        while (g >= 0 && ef[g] >= v) --g;             // g in [-1, 99]
        float Qc = scum[f * NBINS + (g < 0 ? 0 : g)];
        float Pc = (g >= 1) ? scum[f * NBINS + g - 1] : 0.0f;
        sqp[t] = make_float2(Qc, Pc);
    }
    __syncthreads();

    int n = blockIdx.x * 256 + t;
    if (n >= N) return;

    float v[FF];
    const float4* zr = z4 + (size_t)n * 4;
    float4 a0 = zr[0], a1 = zr[1], a2 = zr[2], a3 = zr[3];
    v[0] = a0.x; v[1] = a0.y; v[2]  = a0.z; v[3]  = a0.w;
    v[4] = a1.x; v[5] = a1.y; v[6]  = a1.z; v[7]  = a1.w;
    v[8] = a2.x; v[9] = a2.y; v[10] = a2.z; v[11] = a2.w;
    v[12] = a3.x; v[13] = a3.y; v[14] = a3.z; v[15] = a3.w;

    float Qs[FF], Ps[FF];
#pragma unroll
    for (int f = 0; f < FF; ++f) {
        const float* ef = &se[f * (NBINS + 1)];
        int g = (int)((v[f] - slo[f]) * ss[f]);
        g = g < 0 ? 0 : (g > NBINS - 1 ? NBINS - 1 : g);
        while (g < NBINS - 1 && ef[g + 1] < v[f]) ++g;   // side='left'
        while (g >= 0 && ef[g] >= v[f]) --g;             // g in [-1, 99]
        Qs[f] = scum[f * NBINS + (g < 0 ? 0 : g)];
        Ps[f] = (g >= 1) ? scum[f * NBINS + g - 1] : 0.0f;
    }

    float q[CC];
    float rowsum = 0.0f;
#pragma unroll
    for (int c = 0; c < CC; ++c) {
        float acc = 0.0f;
#pragma unroll
        for (int f = 0; f < FF; ++f) {
            float2 qp = sqp[c * FF + f];       // wave-uniform -> LDS broadcast
            float h = fmaxf(Qs[f], qp.x);
            float l = fminf(Ps[f], qp.y);
            float d = h - l;
            acc = fmaf(d, d, acc);
        }
        float mass = sqrtf(acc) * inv_div;
        float qq = 1.0f / (1.0f + mass);
        q[c] = qq;
        rowsum += qq;
    }

    float* op = out + (size_t)n * CC;
    float4 o;
    o.x = q[0] / rowsum;  o.y = q[1] / rowsum;  o.z = q[2] / rowsum;  o.w = q[3] / rowsum;
    ((float4*)op)[0] = o;
    o.x = q[4] / rowsum;  o.y = q[5] / rowsum;  o.z = q[6] / rowsum;  o.w = q[7] / rowsum;
    ((float4*)op)[1] = o;
    o.x = q[8] / rowsum;  o.y = q[9] / rowsum;  o.z = q[10] / rowsum; o.w = q[11] / rowsum;
    ((float4*)op)[2] = o;
    o.x = q[12] / rowsum; o.y = q[13] / rowsum; o.z = q[14] / rowsum; o.w = q[15] / rowsum;
    ((float4*)op)[3] = o;
}

extern "C" void kernel_launch(void* const* d_in, const int* in_sizes, int n_in,
                              void* d_out, int out_size, void* d_ws, size_t ws_size,
                              hipStream_t stream) {
    const float* z  = (const float*)d_in[0];
    const float* cl = (const float*)d_in[1];
    float* out = (float*)d_out;
    int N = in_sizes[0] / FF;

    char* ws = (char*)d_ws;
    unsigned* partials = (unsigned*)(ws);
    unsigned* counts   = (unsigned*)(ws + 16384);

    int zn4 = N * FF / 4;
    int total4 = (N + CC) * FF / 4;
    float inv_div = 1.0f / (float)(N + CC);

    k_minmax<<<MM_BLOCKS, 256, 0, stream>>>((const float4*)z, (const float4*)cl,
                                            zn4, total4, partials, counts);
    k_hist<<<HIST_BLOCKS, 256, 0, stream>>>((const float4*)z, (const float4*)cl,
                                            zn4, total4, partials, counts);
    int blocks = (N + 255) / 256;
    k_main<<<blocks, 256, 0, stream>>>((const float4*)z, N, inv_div,
                                       partials, counts, cl, out);
}